// Round 2
// baseline (427.224 us; speedup 1.0000x reference)
//
#include <hip/hip_runtime.h>

// ScaledDotProductAttention winner-take-all (B=16, Lq=Lk=2048, D=64, fp32).
// attn = softmax(QK^T/8); mask = (attn == rowmax); attn *= mask; out = attn@V.
// Post-mask attn has ~1 nonzero/row -> QK^T + online top-2 + Z only,
// zero-fill attn inline, scatter winners, out = p * v[winner(s)].
//
// R2: NT=512 (16 waves/CU at 2 blocks/CU), global_load_lds staging with
// source-side swizzle (linear LDS dest), RI=4 x RJ=8 register tile.

namespace {
constexpr int LQn = 2048, LKn = 2048, Dn = 64;
constexpr int QB  = 64;            // q rows per block
constexpr int KBt = 256;           // k rows per LDS tile
constexpr int NT  = 512;           // threads per block (8 waves)
constexpr int NTILES = LKn / KBt;  // 8
// e = exp(s - 10) computed as exp2(acc * (0.125*log2e) - 10*log2e)
constexpr float K1 = 0.125f * 1.44269504088896340736f;
constexpr float K2 = 10.0f  * 1.44269504088896340736f;
}

typedef __attribute__((address_space(3))) void       lds_void_t;
typedef __attribute__((address_space(1))) const void gptr_void_t;

__global__ __launch_bounds__(NT, 4)   // 4 waves/EU -> VGPR<=128 -> 16 waves/CU
void attn_wta(const float* __restrict__ qg, const float* __restrict__ kg,
              const float* __restrict__ vg, float* __restrict__ out_o,
              float* __restrict__ out_a) {
  __shared__ float4 k_s[KBt][16];  // 64 KB, storage col c4 holds logical col c4^(r&7)
  __shared__ float4 q_s[QB][16];   // 16 KB linear; reused after k-loop for row stats
  float* rowP  = (float*)&q_s[0][0];        // overlay (post-final-barrier only)
  int*   rPos1 = (int*)((float*)&q_s[0][0] + 64);
  int*   rPos2 = (int*)((float*)&q_s[0][0] + 128);

  const int t  = threadIdx.x;
  const int l  = t & 63;           // lane
  const int w  = t >> 6;           // wave 0..7
  const int tx = t & 31;           // 32 threads share a q-row group
  const int ty = t >> 5;           // 16 row-groups of 4 rows

  // XCD-bijective swizzle (512 % 8 == 0): each XCD gets 64 consecutive wgs
  // = 2 full batches -> k panel (512 KB) stays L2-local.
  const int wg  = (int)blockIdx.x;
  const int swz = (wg & 7) * 64 + (wg >> 3);
  const int bb  = swz >> 5;         // batch
  const int q0  = (swz & 31) * QB;  // q-tile base row

  const float* qb = qg + ((size_t)bb * LQn + q0) * Dn;
  const float* kb = kg + (size_t)bb * LKn * Dn;
  const float* vb = vg + (size_t)bb * LKn * Dn;
  float* oa = out_a + ((size_t)bb * LQn + q0) * (size_t)LKn;
  float* oo = out_o + ((size_t)bb * LQn + q0) * Dn;

  // ---- stage q tile (1024 float4, linear) via global_load_lds ----
  #pragma unroll
  for (int it = 0; it < 2; ++it) {
    int chunk = it * 8 + w;              // 64-float4 chunk id, wave-uniform
    int f     = chunk * 64 + l;          // this lane's float4 slot
    __builtin_amdgcn_global_load_lds(
        (gptr_void_t*)(qb + (size_t)f * 4),
        (lds_void_t*)(&q_s[0][0] + chunk * 64), 16, 0, 0);
  }

  // per-thread online stats for 4 rows: top-2 (e,pos) + Z partial
  float emax[4], e2nd[4], zsum[4];
  int   pos1[4], pos2[4];
  #pragma unroll
  for (int i = 0; i < 4; ++i) {
    emax[i] = -1.0f; e2nd[i] = -1.0f; zsum[i] = 0.0f; pos1[i] = 0; pos2[i] = 0;
  }

  #pragma unroll 1
  for (int kt = 0; kt < NTILES; ++kt) {
    __syncthreads();  // previous tile's readers done before DMA overwrites k_s
    // ---- stage k tile: 4096 float4, source-swizzled, linear LDS dest ----
    const float* ksrc = kb + (size_t)kt * KBt * Dn;
    #pragma unroll
    for (int it = 0; it < 8; ++it) {
      int chunk = it * 8 + w;            // wave-uniform
      int f  = chunk * 64 + l;
      int r  = f >> 4, c4 = f & 15;
      int dc = c4 ^ (r & 7);             // logical col stored at slot c4
      __builtin_amdgcn_global_load_lds(
          (gptr_void_t*)(ksrc + r * Dn + dc * 4),
          (lds_void_t*)(&k_s[0][0] + chunk * 64), 16, 0, 0);
    }
    __syncthreads();  // vmcnt(0) drain -> k_s (and q_s on kt==0) ready

    // ---- zero-fill attn chunk [64 rows][256 cols]; drains under compute ----
    {
      float4 z4 = make_float4(0.f, 0.f, 0.f, 0.f);
      float* zp = oa + (size_t)kt * KBt + (size_t)(t >> 6) * LKn + (t & 63) * 4;
      #pragma unroll
      for (int it = 0; it < 8; ++it)
        *(float4*)(zp + (size_t)it * 8 * LKn) = z4;
    }

    // ---- 64x256 tile of QK^T: 4x8 per thread, fp32 FMA ----
    float acc[4][8];
    #pragma unroll
    for (int i = 0; i < 4; ++i)
      #pragma unroll
      for (int j = 0; j < 8; ++j) acc[i][j] = 0.0f;

    #pragma unroll 4
    for (int dc = 0; dc < 16; ++dc) {
      const int csw = dc ^ (tx & 7);     // (j*32+tx)&7 == tx&7
      float4 kv[8];
      #pragma unroll
      for (int j = 0; j < 8; ++j)
        kv[j] = k_s[j * 32 + tx][csw];
      #pragma unroll
      for (int i = 0; i < 4; ++i) {
        float4 qv = q_s[ty * 4 + i][dc]; // 2-way broadcast read (free)
        #pragma unroll
        for (int j = 0; j < 8; ++j) {
          acc[i][j] = fmaf(qv.x, kv[j].x, acc[i][j]);
          acc[i][j] = fmaf(qv.y, kv[j].y, acc[i][j]);
          acc[i][j] = fmaf(qv.z, kv[j].z, acc[i][j]);
          acc[i][j] = fmaf(qv.w, kv[j].w, acc[i][j]);
        }
      }
    }

    // ---- fold tile into online stats ----
    const int kt0 = kt * KBt;
    #pragma unroll
    for (int i = 0; i < 4; ++i) {
      float em = emax[i], es = e2nd[i], zz = zsum[i];
      int p1 = pos1[i], p2 = pos2[i];
      #pragma unroll
      for (int j = 0; j < 8; ++j) {
        float e = exp2f(fmaf(acc[i][j], K1, -K2));
        int pos = kt0 + j * 32 + tx;
        bool g1 = e > em, g2 = e > es;
        es = g1 ? em : (g2 ? e : es);
        p2 = g1 ? p1 : (g2 ? pos : p2);
        em = g1 ? e  : em;
        p1 = g1 ? pos : p1;
        zz += e;
      }
      emax[i] = em; e2nd[i] = es; zsum[i] = zz; pos1[i] = p1; pos2[i] = p2;
    }
  }

  // ---- reduce stats across the 32 threads sharing each row ----
  #pragma unroll
  for (int i = 0; i < 4; ++i) {
    float em = emax[i], es = e2nd[i], zz = zsum[i];
    int p1 = pos1[i], p2 = pos2[i];
    #pragma unroll
    for (int m = 16; m >= 1; m >>= 1) {   // masks <32 stay in 32-lane halves
      float oem = __shfl_xor(em, m);
      float oes = __shfl_xor(es, m);
      float ozz = __shfl_xor(zz, m);
      int   op1 = __shfl_xor(p1, m);
      int   op2 = __shfl_xor(p2, m);
      zz += ozz;
      bool g1 = oem > em, g2 = oem > es;
      es = g1 ? em : (g2 ? oem : es);
      p2 = g1 ? p1 : (g2 ? op1 : p2);
      em = g1 ? oem : em;
      p1 = g1 ? op1 : p1;
      bool h2 = oes > es;                 // oes <= new em always
      es = h2 ? oes : es;
      p2 = h2 ? op2 : p2;
    }
    emax[i] = em; e2nd[i] = es; zsum[i] = zz; pos1[i] = p1; pos2[i] = p2;
  }

  __syncthreads();  // all q_s reads done; all zero-stores drained (vmcnt 0)

  if (tx == 0) {
    #pragma unroll
    for (int i = 0; i < 4; ++i) {
      int r = ty * 4 + i;
      float p  = emax[i] / zsum[i];
      float p2 = e2nd[i] / zsum[i];
      rowP[r]  = p;
      rPos1[r] = pos1[i];
      rPos2[r] = (p2 == p) ? pos2[i] : -1;  // prob-level tie like reference
    }
  }
  __syncthreads();

  // ---- winner scatter into attn (ordered after zero-fill by barriers) ----
  if (t < QB) {
    float p = rowP[t];
    float* ar = oa + (size_t)t * LKn;
    ar[rPos1[t]] = p;
    int w2 = rPos2[t];
    if (w2 >= 0) ar[w2] = p;
  }

  // ---- output rows: out[r,:] = p * v[w1,:] (+ p * v[w2,:]) ----
  #pragma unroll
  for (int it = 0; it < 2; ++it) {
    int slot = it * NT + t;              // 1024 slots = 64 rows x 16 float4
    int r = slot >> 4, c4 = slot & 15;
    float p = rowP[r];
    int w1 = rPos1[r], w2 = rPos2[r];
    const float4 v1 = *(const float4*)(vb + (size_t)w1 * Dn + c4 * 4);
    float4 o;
    o.x = p * v1.x; o.y = p * v1.y; o.z = p * v1.z; o.w = p * v1.w;
    if (w2 >= 0) {
      const float4 v2 = *(const float4*)(vb + (size_t)w2 * Dn + c4 * 4);
      o.x += p * v2.x; o.y += p * v2.y; o.z += p * v2.z; o.w += p * v2.w;
    }
    *(float4*)(oo + (size_t)r * Dn + c4 * 4) = o;
  }
}

extern "C" void kernel_launch(void* const* d_in, const int* in_sizes, int n_in,
                              void* d_out, int out_size, void* d_ws, size_t ws_size,
                              hipStream_t stream) {
  const float* q = (const float*)d_in[0];
  const float* k = (const float*)d_in[1];
  const float* v = (const float*)d_in[2];
  float* out_o = (float*)d_out;                                   // [16,2048,64]
  float* out_a = (float*)d_out + (size_t)16 * 2048 * 64;          // [16,2048,2048]
  hipLaunchKernelGGL(attn_wta, dim3(16 * (LQn / QB)), dim3(NT), 0, stream,
                     q, k, v, out_o, out_a);
}

// Round 3
// 310.301 us; speedup vs baseline: 1.3768x; 1.3768x over previous
//
#include <hip/hip_runtime.h>

// ScaledDotProductAttention winner-take-all (B=16, Lq=Lk=2048, D=64, fp32).
// attn = softmax(QK^T/8); mask = (attn == rowmax); attn *= mask; out = attn@V.
// Post-mask attn has ~1 nonzero/row -> QK^T + online top-2 + Z only.
//
// R3: fp16 two-term split (lo prescaled x4096, no denormals) + swapped MFMA
// (K as A, Q as B -> each lane owns one q-column; stats lane-local).
// Pre-pass packs Q/K split halves in fragment order so the main loop reads
// operands via coalesced global loads: no LDS, no barriers in the k-loop.

namespace {
constexpr int LQn = 2048, LKn = 2048, Dn = 64;
constexpr int QB  = 64;            // q rows per block (2 groups of 32)
constexpr int NT  = 256;           // 4 waves: (q-group x k-half)
// e = exp(s/8 - 10) = exp2(s*K1 - K2)
constexpr float K1 = 0.125f * 1.44269504088896340736f;
constexpr float K2 = 10.0f  * 1.44269504088896340736f;
constexpr float CSC = 1.0f / 4096.0f;   // cross-term descale
}

typedef _Float16 half8  __attribute__((ext_vector_type(8)));
typedef float    f32x16 __attribute__((ext_vector_type(16)));

// ---------------- pre-pass: split fp32 -> (hi, lo*4096) fp16 fragments ------
// Layout: buf[(b*64 + grp)*8 + c][lane][8 f16]; c<4: hi chunk c, c>=4: lo c-4.
// Fragment semantics (32x32x16): lane l supplies rows/cols (l&31), dims
// c4*16 + (l>>5)*8 + e  (same formula for A and B -> k-permutation cancels).
__global__ __launch_bounds__(256)
void split_pack(const float* __restrict__ src_q, const float* __restrict__ src_k,
                half8* __restrict__ qhl, half8* __restrict__ khl) {
  const int t = threadIdx.x, l = t & 63, w = t >> 6;
  const int gid = blockIdx.x * 4 + w;          // 0..2047
  const int tensor = gid >> 10;                // 0 = Q, 1 = K
  const int rem = gid & 1023;
  const int b = rem >> 6, grp = rem & 63;
  const float* src = (tensor ? src_k : src_q) +
                     ((size_t)b * 2048 + grp * 32 + (l & 31)) * Dn;
  half8* dst = (tensor ? khl : qhl) + ((size_t)(b * 64 + grp) * 8) * 64 + l;
  const int dhalf = (l >> 5) * 8;
  #pragma unroll
  for (int c4 = 0; c4 < 4; ++c4) {
    const float* s8 = src + c4 * 16 + dhalf;
    float4 x0 = *(const float4*)s8;
    float4 x1 = *(const float4*)(s8 + 4);
    float xs[8] = {x0.x, x0.y, x0.z, x0.w, x1.x, x1.y, x1.z, x1.w};
    half8 hh, ll;
    #pragma unroll
    for (int e = 0; e < 8; ++e) {
      float x = xs[e];
      _Float16 h = (_Float16)x;
      float r = x - (float)h;                  // exact
      hh[e] = h;
      ll[e] = (_Float16)(r * 4096.0f);         // normalized, no f16 denorm
    }
    dst[(size_t)c4 * 64]       = hh;
    dst[(size_t)(4 + c4) * 64] = ll;
  }
}

// ---------------- main: MFMA QK^T + online top-2 + Z, barrier-free loop -----
__global__ __launch_bounds__(NT, 2)
void attn_wta_mfma(const half8* __restrict__ qhl, const half8* __restrict__ khl,
                   const float* __restrict__ vg, float* __restrict__ out_o,
                   float* __restrict__ out_a) {
  __shared__ float em_s[128], es_s[128], zz_s[128];
  __shared__ int   p1_s[128], p2_s[128];
  __shared__ float rowP[QB];
  __shared__ int   rW1[QB], rW2[QB];

  const int t = threadIdx.x, l = t & 63, w = t >> 6;
  const int hi = l >> 5;

  // XCD-bijective swizzle (512 % 8 == 0): 64 consecutive wgs per XCD = 2 batches.
  const int wg  = (int)blockIdx.x;
  const int swz = (wg & 7) * 64 + (wg >> 3);
  const int bb  = swz >> 5;          // batch
  const int qt  = swz & 31;          // q-tile (64 rows)
  const int q0  = qt * QB;
  const int qg2 = w & 1;             // q-group within tile
  const int kh2 = w >> 1;            // k half (1024 rows = 32 tiles)
  const int qg  = qt * 2 + qg2;      // global q-group 0..63

  // Q fragments: 8 chunks (hi c4=0..3, lo c4=0..3), stay in VGPRs all kernel.
  const half8* qp = qhl + (((size_t)bb * 64 + qg) * 8) * 64 + l;
  half8 qf[8];
  #pragma unroll
  for (int c = 0; c < 8; ++c) qf[c] = qp[(size_t)c * 64];

  float em = -1.0f, es = -1.0f, zz = 0.0f;
  int   p1 = 0, p2 = 0;

  const half8* kp = khl + (((size_t)bb * 64 + kh2 * 32) * 8) * 64 + l;
  float* oa = out_a + ((size_t)bb * LQn + q0) * (size_t)LKn;
  const float4 z4 = make_float4(0.f, 0.f, 0.f, 0.f);

  half8 af[8];
  #pragma unroll
  for (int c = 0; c < 8; ++c) af[c] = kp[(size_t)c * 64];

  #pragma unroll 1
  for (int it = 0; it < 32; ++it) {
    // prefetch next k-tile fragments (registers, 1-deep)
    half8 an[8];
    {
      int nx = it + 1 < 32 ? it + 1 : 31;
      const half8* np_ = kp + (size_t)nx * 8 * 64;
      #pragma unroll
      for (int c = 0; c < 8; ++c) an[c] = np_[(size_t)c * 64];
    }
    // zero-fill slice of attn region (drains under compute; barrier orders it
    // before the winner scatter)
    #pragma unroll
    for (int j = 0; j < 4; ++j) {
      int f = it * 1024 + j * 256 + t;         // 32768 float4 = 64 x 2048
      *(float4*)(oa + (size_t)f * 4) = z4;
    }
    // 12 MFMAs: hh -> ah ; (hi*lo' + lo'*hi) -> ac (descale by 2^-12 later)
    f32x16 ah, ac;
    #pragma unroll
    for (int r = 0; r < 16; ++r) { ah[r] = 0.0f; ac[r] = 0.0f; }
    #pragma unroll
    for (int c4 = 0; c4 < 4; ++c4) {
      ah = __builtin_amdgcn_mfma_f32_32x32x16_f16(af[c4],     qf[c4],     ah, 0, 0, 0);
      ac = __builtin_amdgcn_mfma_f32_32x32x16_f16(af[c4],     qf[4 + c4], ac, 0, 0, 0);
      ac = __builtin_amdgcn_mfma_f32_32x32x16_f16(af[4 + c4], qf[c4],     ac, 0, 0, 0);
    }
    // fold 16 lane-local scores (this lane's q-column) into top-2 + Z
    const int kbase = (kh2 * 32 + it) * 32;
    #pragma unroll
    for (int r = 0; r < 16; ++r) {
      float s = fmaf(ac[r], CSC, ah[r]);
      float e = exp2f(fmaf(s, K1, -K2));
      int pos = kbase + (r & 3) + 8 * (r >> 2) + 4 * hi;
      bool g1 = e > em, g2 = e > es;
      es = g1 ? em : (g2 ? e : es);
      p2 = g1 ? p1 : (g2 ? pos : p2);
      em = g1 ? e : em;
      p1 = g1 ? pos : p1;
      zz += e;
    }
    #pragma unroll
    for (int c = 0; c < 8; ++c) af[c] = an[c];
  }

  // merge lane pairs (l, l+32): same q-column, disjoint k rows
  {
    float oem = __shfl_xor(em, 32, 64);
    float oes = __shfl_xor(es, 32, 64);
    float ozz = __shfl_xor(zz, 32, 64);
    int   op1 = __shfl_xor(p1, 32, 64);
    int   op2 = __shfl_xor(p2, 32, 64);
    zz += ozz;
    bool g1 = oem > em, g2 = oem > es;
    es = g1 ? em : (g2 ? oem : es);
    p2 = g1 ? p1 : (g2 ? op1 : p2);
    em = g1 ? oem : em;
    p1 = g1 ? op1 : p1;
    bool h2 = oes > es;
    es = h2 ? oes : es;
    p2 = h2 ? op2 : p2;
  }
  if (l < 32) {
    int idx = w * 32 + l;
    em_s[idx] = em; es_s[idx] = es; zz_s[idx] = zz;
    p1_s[idx] = p1; p2_s[idx] = p2;
  }
  __syncthreads();   // also drains all zero-fill stores (vmcnt 0)

  if (t < QB) {
    int g = t >> 5, q = t & 31;
    int ia = g * 32 + q;          // wave g   : k rows 0..1023
    int ib = (2 + g) * 32 + q;    // wave 2+g : k rows 1024..2047
    float ema = em_s[ia], esa = es_s[ia], emb = em_s[ib], esb = es_s[ib];
    float Z = zz_s[ia] + zz_s[ib];
    int pa1 = p1_s[ia], pa2 = p2_s[ia], pb1 = p1_s[ib], pb2 = p2_s[ib];
    float m1, m2; int w1, w2;
    if (emb > ema) {
      m1 = emb; w1 = pb1;
      m2 = (ema > esb) ? ema : esb; w2 = (ema > esb) ? pa1 : pb2;
    } else {
      m1 = ema; w1 = pa1;
      m2 = (emb > esa) ? emb : esa; w2 = (emb > esa) ? pb1 : pa2;
    }
    float p  = m1 / Z;
    float ps = m2 / Z;
    int wsec = (ps == p) ? w2 : -1;  // prob-level tie, like reference
    rowP[t] = p; rW1[t] = w1; rW2[t] = wsec;
    float* ar = oa + (size_t)t * LKn;
    ar[w1] = p;
    if (wsec >= 0) ar[wsec] = p;
  }
  __syncthreads();

  // output rows: out[r,:] = p * v[w1,:] (+ p * v[w2,:])
  const float* vb = vg + (size_t)bb * LKn * Dn;
  float* oo = out_o + ((size_t)bb * LQn + q0) * Dn;
  #pragma unroll
  for (int j = 0; j < 4; ++j) {
    int slot = j * 256 + t;              // 1024 slots = 64 rows x 16 float4
    int r = slot >> 4, c4 = slot & 15;
    float p = rowP[r];
    int w1 = rW1[r], w2 = rW2[r];
    float4 v1 = *(const float4*)(vb + (size_t)w1 * Dn + c4 * 4);
    float4 o = make_float4(p * v1.x, p * v1.y, p * v1.z, p * v1.w);
    if (w2 >= 0) {
      float4 v2 = *(const float4*)(vb + (size_t)w2 * Dn + c4 * 4);
      o.x += p * v2.x; o.y += p * v2.y; o.z += p * v2.z; o.w += p * v2.w;
    }
    *(float4*)(oo + (size_t)r * Dn + c4 * 4) = o;
  }
}

// ---------------- fallback (proven R1 kernel) if ws too small ---------------
__global__ __launch_bounds__(256, 2)
void attn_wta_fp32(const float* __restrict__ qg, const float* __restrict__ kg,
                   const float* __restrict__ vg, float* __restrict__ out_o,
                   float* __restrict__ out_a) {
  __shared__ float4 k_s[256][16];
  __shared__ float  q_s[64][64];
  float* rowP  = &q_s[0][0];
  int*   rPos1 = (int*)&q_s[1][0];
  int*   rPos2 = (int*)&q_s[2][0];
  const int t = threadIdx.x, tx = t & 31, ty = t >> 5;
  const int wg = (int)blockIdx.x;
  const int swz = (wg & 7) * 64 + (wg >> 3);
  const int bb = swz >> 5, q0 = (swz & 31) * 64;
  const float* qb = qg + ((size_t)bb * LQn + q0) * Dn;
  const float* kb = kg + (size_t)bb * LKn * Dn;
  const float* vb = vg + (size_t)bb * LKn * Dn;
  float* oa = out_a + ((size_t)bb * LQn + q0) * (size_t)LKn;
  float* oo = out_o + ((size_t)bb * LQn + q0) * Dn;
  #pragma unroll
  for (int it = 0; it < 4; ++it) {
    int slot = it * 256 + t, r = slot >> 4, c4 = slot & 15;
    *(float4*)&q_s[r][c4 * 4] = *(const float4*)(qb + r * Dn + c4 * 4);
  }
  float emax[8], e2nd[8], zsum[8]; int pos1[8], pos2[8];
  #pragma unroll
  for (int i = 0; i < 8; ++i) { emax[i] = -1.f; e2nd[i] = -1.f; zsum[i] = 0.f; pos1[i] = 0; pos2[i] = 0; }
  float* zbase = oa + (size_t)(t >> 6) * LKn + (t & 63) * 4;
  #pragma unroll 1
  for (int kt = 0; kt < 8; ++kt) {
    __syncthreads();
    const float* ksrc = kb + (size_t)kt * 256 * Dn;
    #pragma unroll
    for (int it = 0; it < 16; ++it) {
      int slot = it * 256 + t, r = slot >> 4, c4 = slot & 15;
      k_s[r][c4 ^ (r & 7)] = *(const float4*)(ksrc + r * Dn + c4 * 4);
    }
    __syncthreads();
    float4 z4 = make_float4(0.f, 0.f, 0.f, 0.f);
    float* zp = zbase + (size_t)kt * 256;
    #pragma unroll
    for (int it = 0; it < 16; ++it) *(float4*)(zp + (size_t)it * 4 * LKn) = z4;
    float acc[8][8];
    #pragma unroll
    for (int i = 0; i < 8; ++i)
      #pragma unroll
      for (int j = 0; j < 8; ++j) acc[i][j] = 0.f;
    #pragma unroll 4
    for (int dc = 0; dc < 16; ++dc) {
      float4 qv[8], kv[8];
      #pragma unroll
      for (int i = 0; i < 8; ++i) qv[i] = *(const float4*)&q_s[ty * 8 + i][dc * 4];
      const int csw = dc ^ (tx & 7);
      #pragma unroll
      for (int j = 0; j < 8; ++j) kv[j] = k_s[j * 32 + tx][csw];
      #pragma unroll
      for (int i = 0; i < 8; ++i)
        #pragma unroll
        for (int j = 0; j < 8; ++j) {
          acc[i][j] = fmaf(qv[i].x, kv[j].x, acc[i][j]);
          acc[i][j] = fmaf(qv[i].y, kv[j].y, acc[i][j]);
          acc[i][j] = fmaf(qv[i].z, kv[j].z, acc[i][j]);
          acc[i][j] = fmaf(qv[i].w, kv[j].w, acc[i][j]);
        }
    }
    const int kt0 = kt * 256;
    #pragma unroll
    for (int i = 0; i < 8; ++i) {
      float em = emax[i], es = e2nd[i], zq = zsum[i];
      int p1 = pos1[i], p2 = pos2[i];
      #pragma unroll
      for (int j = 0; j < 8; ++j) {
        float e = exp2f(fmaf(acc[i][j], K1, -K2));
        int pos = kt0 + j * 32 + tx;
        bool g1 = e > em, g2 = e > es;
        es = g1 ? em : (g2 ? e : es);
        p2 = g1 ? p1 : (g2 ? pos : p2);
        em = g1 ? e : em;
        p1 = g1 ? pos : p1;
        zq += e;
      }
      emax[i] = em; e2nd[i] = es; zsum[i] = zq; pos1[i] = p1; pos2[i] = p2;
    }
  }
  #pragma unroll
  for (int i = 0; i < 8; ++i) {
    float em = emax[i], es = e2nd[i], zq = zsum[i];
    int p1 = pos1[i], p2 = pos2[i];
    #pragma unroll
    for (int m = 16; m >= 1; m >>= 1) {
      float oem = __shfl_xor(em, m); float oes = __shfl_xor(es, m);
      float ozz = __shfl_xor(zq, m);
      int op1 = __shfl_xor(p1, m); int op2 = __shfl_xor(p2, m);
      zq += ozz;
      bool g1 = oem > em, g2 = oem > es;
      es = g1 ? em : (g2 ? oem : es);
      p2 = g1 ? p1 : (g2 ? op1 : p2);
      em = g1 ? oem : em; p1 = g1 ? op1 : p1;
      bool h2 = oes > es;
      es = h2 ? oes : es; p2 = h2 ? op2 : p2;
    }
    emax[i] = em; e2nd[i] = es; zsum[i] = zq; pos1[i] = p1; pos2[i] = p2;
  }
  __syncthreads();
  if (tx == 0) {
    #pragma unroll
    for (int i = 0; i < 8; ++i) {
      int r = ty * 8 + i;
      float p = emax[i] / zsum[i], p2v = e2nd[i] / zsum[i];
      rowP[r] = p; rPos1[r] = pos1[i]; rPos2[r] = (p2v == p) ? pos2[i] : -1;
    }
  }
  __syncthreads();
  if (t < 64) {
    float p = rowP[t];
    float* ar = oa + (size_t)t * LKn;
    ar[rPos1[t]] = p;
    if (rPos2[t] >= 0) ar[rPos2[t]] = p;
  }
  #pragma unroll
  for (int it = 0; it < 4; ++it) {
    int slot = it * 256 + t, r = slot >> 4, c4 = slot & 15;
    float p = rowP[r];
    int w1 = rPos1[r], w2 = rPos2[r];
    float4 v1 = *(const float4*)(vb + (size_t)w1 * Dn + c4 * 4);
    float4 o = make_float4(p * v1.x, p * v1.y, p * v1.z, p * v1.w);
    if (w2 >= 0) {
      float4 v2 = *(const float4*)(vb + (size_t)w2 * Dn + c4 * 4);
      o.x += p * v2.x; o.y += p * v2.y; o.z += p * v2.z; o.w += p * v2.w;
    }
    *(float4*)(oo + (size_t)r * Dn + c4 * 4) = o;
  }
}

extern "C" void kernel_launch(void* const* d_in, const int* in_sizes, int n_in,
                              void* d_out, int out_size, void* d_ws, size_t ws_size,
                              hipStream_t stream) {
  const float* q = (const float*)d_in[0];
  const float* k = (const float*)d_in[1];
  const float* v = (const float*)d_in[2];
  float* out_o = (float*)d_out;                                  // [16,2048,64]
  float* out_a = (float*)d_out + (size_t)16 * 2048 * 64;         // [16,2048,2048]
  if (ws_size >= (size_t)16777216) {
    half8* qhl = (half8*)d_ws;                                   // 8 MB
    half8* khl = qhl + (size_t)524288;                           // 8 MB
    hipLaunchKernelGGL(split_pack, dim3(512), dim3(256), 0, stream, q, k, qhl, khl);
    hipLaunchKernelGGL(attn_wta_mfma, dim3(512), dim3(NT), 0, stream,
                       qhl, khl, v, out_o, out_a);
  } else {
    hipLaunchKernelGGL(attn_wta_fp32, dim3(512), dim3(256), 0, stream,
                       q, k, v, out_o, out_a);
  }
}